// Round 1
// baseline (343.555 us; speedup 1.0000x reference)
//
#include <hip/hip_runtime.h>
#include <math.h>

// Quantum circuit simulation, N=20 qubits, 4 layers, batch 16.
// State is purely real (real input, real RY, CNOT permutation) -> float32 sim.
// qubit q <-> bit (19-q) of flat index. Per layer:
//   H-pass: RY(0..5) + CNOT(0,1)..(4,5)   on bits 19..14 (register pass)
//   T-pass: RY(6..19) + CNOT(5,6)..(18,19) on bits 13..0 (LDS chunk pass)

__global__ __launch_bounds__(256) void hpass_kernel(
    const float* __restrict__ in, float* __restrict__ out,
    const float* __restrict__ theta, int layer)
{
    int idx = blockIdx.x * 256 + threadIdx.x;     // 0 .. 16*2^14 - 1
    int b   = idx >> 14;
    int low = idx & 16383;
    size_t base = ((size_t)b << 20) + (size_t)low;
    const float* src = in + base;

    float v[64];
#pragma unroll
    for (int m = 0; m < 64; ++m) v[m] = src[(size_t)m << 14];

    // RY on qubit q (0..5): pair bit = m bit (5-q), a = bit-clear element
#pragma unroll
    for (int q = 0; q < 6; ++q) {
        float s, c; sincosf(theta[layer * 20 + q] * 0.5f, &s, &c);
        int mask = 1 << (5 - q);
#pragma unroll
        for (int m = 0; m < 64; ++m) {
            if (!(m & mask)) {
                float a = v[m], bv = v[m | mask];
                v[m]        = c * a - s * bv;
                v[m | mask] = s * a + c * bv;
            }
        }
    }
    // CNOT(q,q+1) q=0..4: control m bit (5-q), target m bit (4-q)
#pragma unroll
    for (int q = 0; q < 5; ++q) {
        int cm = 1 << (5 - q), tm = 1 << (4 - q);
#pragma unroll
        for (int m = 0; m < 64; ++m) {
            if ((m & cm) && !(m & tm)) {
                float tmp = v[m]; v[m] = v[m | tm]; v[m | tm] = tmp;
            }
        }
    }

    float* dst = out + base;
#pragma unroll
    for (int m = 0; m < 64; ++m) dst[(size_t)m << 14] = v[m];
}

template <bool DO_ABS>
__global__ __launch_bounds__(256) void tpass_kernel(
    const float* __restrict__ in, float* __restrict__ out,
    const float* __restrict__ theta, int layer)
{
    __shared__ float lds[16384];                  // 64 KiB chunk
    int t = threadIdx.x;
    int chunk    = blockIdx.x;                    // 0..1023
    int b        = chunk >> 6;
    int chunkIdx = chunk & 63;                    // global bits 19..14
    size_t base = ((size_t)b << 20) + ((size_t)chunkIdx << 14);
    const float* src = in + base;
    const float* th  = theta + layer * 20;

    float v[64];

    // ---- Round A: thread holds j = m*256 + t  (m = bits 13..8) ----
#pragma unroll
    for (int m = 0; m < 64; ++m) v[m] = src[m * 256 + t];

    // RY q=6..11: m bit (11-q)
#pragma unroll
    for (int q = 6; q < 12; ++q) {
        float s, c; sincosf(th[q] * 0.5f, &s, &c);
        int mask = 1 << (11 - q);
#pragma unroll
        for (int m = 0; m < 64; ++m) {
            if (!(m & mask)) {
                float a = v[m], bv = v[m | mask];
                v[m]        = c * a - s * bv;
                v[m | mask] = s * a + c * bv;
            }
        }
    }
    // CNOT(5,6): control = global bit 14 = chunkIdx bit 0, target = m bit 5
    if (chunkIdx & 1) {
#pragma unroll
        for (int m = 0; m < 32; ++m) { float tmp = v[m]; v[m] = v[m | 32]; v[m | 32] = tmp; }
    }
    // CNOT(q,q+1) q=6..10: control m bit (11-q), target m bit (10-q)
#pragma unroll
    for (int q = 6; q < 11; ++q) {
        int cm = 1 << (11 - q), tm = 1 << (10 - q);
#pragma unroll
        for (int m = 0; m < 64; ++m) {
            if ((m & cm) && !(m & tm)) {
                float tmp = v[m]; v[m] = v[m | tm]; v[m | tm] = tmp;
            }
        }
    }
    // exchange via layout-1: addr1(j) = j ^ (((j>>8)&7)<<2)
#pragma unroll
    for (int m = 0; m < 64; ++m) {
        int j = m * 256 + t;
        lds[j ^ ((m & 7) << 2)] = v[m];
    }
    __syncthreads();

    // ---- Round B: thread holds j = f6*256 + k*4 + f2  (k = bits 7..2) ----
    int f6 = t >> 2, f2 = t & 3;
#pragma unroll
    for (int k = 0; k < 64; ++k) {
        int j = f6 * 256 + k * 4 + f2;
        v[k] = lds[j ^ ((f6 & 7) << 2)];
    }
    // RY q=12..17: k bit (17-q)
#pragma unroll
    for (int q = 12; q < 18; ++q) {
        float s, c; sincosf(th[q] * 0.5f, &s, &c);
        int mask = 1 << (17 - q);
#pragma unroll
        for (int k = 0; k < 64; ++k) {
            if (!(k & mask)) {
                float a = v[k], bv = v[k | mask];
                v[k]        = c * a - s * bv;
                v[k | mask] = s * a + c * bv;
            }
        }
    }
    // CNOT(11,12): control = global bit 8 = f6 bit 0, target = k bit 5
    if (f6 & 1) {
#pragma unroll
        for (int k = 0; k < 32; ++k) { float tmp = v[k]; v[k] = v[k | 32]; v[k | 32] = tmp; }
    }
    // CNOT(q,q+1) q=12..16: control k bit (17-q), target k bit (16-q)
#pragma unroll
    for (int q = 12; q < 17; ++q) {
        int cm = 1 << (17 - q), tm = 1 << (16 - q);
#pragma unroll
        for (int k = 0; k < 64; ++k) {
            if ((k & cm) && !(k & tm)) {
                float tmp = v[k]; v[k] = v[k | tm]; v[k | tm] = tmp;
            }
        }
    }
    __syncthreads();
    // exchange via layout-2: addr2(j) = j ^ ((j>>6)&31)
#pragma unroll
    for (int k = 0; k < 64; ++k) {
        int j = f6 * 256 + k * 4 + f2;
        lds[j ^ ((j >> 6) & 31)] = v[k];
    }
    __syncthreads();

    // ---- Round C: thread holds j = t*64 + k  (k = bits 5..0) ----
#pragma unroll
    for (int k = 0; k < 64; ++k) {
        int j = t * 64 + k;
        v[k] = lds[j ^ ((j >> 6) & 31)];
    }
    // RY q=18 (k bit 1), q=19 (k bit 0)
#pragma unroll
    for (int q = 18; q < 20; ++q) {
        float s, c; sincosf(th[q] * 0.5f, &s, &c);
        int mask = 1 << (19 - q);
#pragma unroll
        for (int k = 0; k < 64; ++k) {
            if (!(k & mask)) {
                float a = v[k], bv = v[k | mask];
                v[k]        = c * a - s * bv;
                v[k | mask] = s * a + c * bv;
            }
        }
    }
    // CNOT(17,18): control k bit 2, target k bit 1
#pragma unroll
    for (int k = 0; k < 64; ++k)
        if ((k & 4) && !(k & 2)) { float tmp = v[k]; v[k] = v[k | 2]; v[k | 2] = tmp; }
    // CNOT(18,19): control k bit 1, target k bit 0
#pragma unroll
    for (int k = 0; k < 64; ++k)
        if ((k & 2) && !(k & 1)) { float tmp = v[k]; v[k] = v[k | 1]; v[k | 1] = tmp; }
    // write back own elements (same addresses we read -> no barrier needed)
#pragma unroll
    for (int k = 0; k < 64; ++k) {
        int j = t * 64 + k;
        lds[j ^ ((j >> 6) & 31)] = v[k];
    }
    __syncthreads();

    // ---- final repack: read j = m*256 + t, coalesced global store ----
    float* dst = out + base;
#pragma unroll
    for (int m = 0; m < 64; ++m) {
        int j = m * 256 + t;
        float val = lds[j ^ ((j >> 6) & 31)];
        if (DO_ABS) val = fabsf(val);
        dst[j] = val;
    }
}

extern "C" void kernel_launch(void* const* d_in, const int* in_sizes, int n_in,
                              void* d_out, int out_size, void* d_ws, size_t ws_size,
                              hipStream_t stream) {
    const float* x     = (const float*)d_in[0];   // (16, 2^20) float32
    const float* theta = (const float*)d_in[1];   // (80,) float32
    float* st = (float*)d_out;                    // state lives in d_out (in-place passes)

    dim3 grid(1024), block(256);
    for (int l = 0; l < 4; ++l) {
        hpass_kernel<<<grid, block, 0, stream>>>(l == 0 ? x : st, st, theta, l);
        if (l < 3)
            tpass_kernel<false><<<grid, block, 0, stream>>>(st, st, theta, l);
        else
            tpass_kernel<true><<<grid, block, 0, stream>>>(st, st, theta, l);
    }
}